// Round 7
// baseline (53.968 us; speedup 1.0000x reference)
//
#include <hip/hip_runtime.h>
#include <hip/hip_bf16.h>
#include <math.h>

#define Bn 4096
#define Ln 50
#define Cn 100
#define Tn 50000
#define Dn 128
#define H1n 256
#define H2n 128
#define ROWS 4                    // batch rows per mlp block (4 blocks/CU)

#define NTBLK (Tn / 4)            // 12500 table-prep blocks (4 waves, 1 row each)
#define NWPREP 384                // (256*256 + 128*256) / 256 weight-prep blocks

typedef __attribute__((ext_vector_type(8))) short short8;
typedef __attribute__((ext_vector_type(4))) float f32x4;

// ---------------------------------------------------------------------------
// Kernel 1 (unchanged from round 6): table bf16 cast + tag_score + weight prep
// ---------------------------------------------------------------------------
__global__ __launch_bounds__(256) void prep_kernel(
    const float* __restrict__ table, const float* __restrict__ Wr,
    const float* __restrict__ W1, const float* __restrict__ W2,
    float* __restrict__ tag_score, __hip_bfloat16* __restrict__ tableB,
    __hip_bfloat16* __restrict__ W1T, __hip_bfloat16* __restrict__ W2T) {
  const int blk = blockIdx.x;
  const int tid = threadIdx.x;

  if (blk < NTBLK) {
    const int t = blk * 4 + (tid >> 6);   // one wave per table row
    const int lane = tid & 63;
    const float2 v = *reinterpret_cast<const float2*>(table + (size_t)t * Dn + lane * 2);
    const float2 w = *reinterpret_cast<const float2*>(Wr + H2n + lane * 2);
    __hip_bfloat162 o;
    o.x = __float2bfloat16(v.x);
    o.y = __float2bfloat16(v.y);
    *reinterpret_cast<__hip_bfloat162*>(tableB + (size_t)t * Dn + lane * 2) = o;
    float acc = v.x * w.x + v.y * w.y;
#pragma unroll
    for (int m = 32; m >= 1; m >>= 1) acc += __shfl_xor(acc, m, 64);
    if (lane == 0) tag_score[t] = acc;
  } else {
    int id = (blk - NTBLK) * 256 + tid;
    if (id < H1n * H1n) {
      const int j = id >> 8, k = id & 255;
      W1T[(size_t)j * (2 * Dn) + k] = __float2bfloat16(W1[(size_t)k * H1n + j]);
    } else {
      id -= H1n * H1n;
      const int j = id >> 8, k = id & 255;  // j < 128, k < 256
      W2T[(size_t)j * H1n + k] = __float2bfloat16(W2[(size_t)k * H2n + j]);
    }
  }
}

// ---------------------------------------------------------------------------
// Kernel 2 (unchanged from round 6): masked-mean pooling
// ---------------------------------------------------------------------------
__global__ __launch_bounds__(256) void pool_kernel(
    const int* __restrict__ user_tags, const int* __restrict__ user_len,
    const int* __restrict__ item_tags, const int* __restrict__ item_len,
    const __hip_bfloat16* __restrict__ tableB, __hip_bfloat16* __restrict__ x_out) {
  __shared__ int s_tags[2][Ln];
  __shared__ float2 s_acc[2][64];
  const int b = blockIdx.x;
  const int tid = threadIdx.x;

  if (tid < Ln) s_tags[0][tid] = user_tags[b * Ln + tid];
  else if (tid >= 128 && tid < 128 + Ln) s_tags[1][tid - 128] = item_tags[b * Ln + (tid - 128)];
  __syncthreads();

  const int w = tid >> 6;         // wave 0..3
  const int half = w >> 1;        // 0 = user, 1 = item
  const int par = w & 1;          // position parity handled by this wave
  const int lane = tid & 63;
  const int len = half ? item_len[b] : user_len[b];
  const int* tags = s_tags[half];

  const __hip_bfloat162* base =
      reinterpret_cast<const __hip_bfloat162*>(tableB) + lane;  // + t*64

  float a0 = 0.f, a1 = 0.f;
  int l = par;
  for (; l + 14 < len; l += 16) {
    __hip_bfloat162 v[8];
#pragma unroll
    for (int q = 0; q < 8; ++q) v[q] = base[(size_t)tags[l + 2 * q] * 64];
#pragma unroll
    for (int q = 0; q < 8; ++q) {
      a0 += __bfloat162float(v[q].x);
      a1 += __bfloat162float(v[q].y);
    }
  }
  for (; l + 6 < len; l += 8) {
    __hip_bfloat162 v[4];
#pragma unroll
    for (int q = 0; q < 4; ++q) v[q] = base[(size_t)tags[l + 2 * q] * 64];
#pragma unroll
    for (int q = 0; q < 4; ++q) {
      a0 += __bfloat162float(v[q].x);
      a1 += __bfloat162float(v[q].y);
    }
  }
  for (; l < len; l += 2) {
    const __hip_bfloat162 v = base[(size_t)tags[l] * 64];
    a0 += __bfloat162float(v.x);
    a1 += __bfloat162float(v.y);
  }

  if (par == 1) s_acc[half][lane] = make_float2(a0, a1);
  __syncthreads();
  if (par == 0) {
    a0 += s_acc[half][lane].x;
    a1 += s_acc[half][lane].y;
    const float inv = 1.f / (float)(len > 0 ? len : 1);
    __hip_bfloat162 o;
    o.x = __float2bfloat16(a0 * inv);
    o.y = __float2bfloat16(a1 * inv);
    *reinterpret_cast<__hip_bfloat162*>(
        x_out + (size_t)b * (2 * Dn) + half * Dn + 2 * lane) = o;
  }
}

// ---------------------------------------------------------------------------
// Kernel 3: MFMA MLP + scoring. 256 threads (4 waves), 4 batch rows/block,
// 1024 blocks => 4 blocks/CU for cross-block latency hiding.
// A-tile rows duplicated 4x via (lr&3): D row i <-> batch row (i&3).
//   layer1: wave w covers cols [w*64, w*64+64)   (4 tiles x 8 K-steps)
//   layer2: wave w covers cols [w*32, w*32+32)   (2 tiles x 8 K-steps)
// mfma_f32_16x16x32_bf16 layouts (m89-verified, unchanged from round 4).
// ---------------------------------------------------------------------------
__global__ __launch_bounds__(256) void mlp_mfma_kernel(
    const __hip_bfloat16* __restrict__ x_in, const __hip_bfloat16* __restrict__ W1T,
    const float* __restrict__ b1, const __hip_bfloat16* __restrict__ W2T,
    const float* __restrict__ b2, const float* __restrict__ Wr,
    const float* __restrict__ br, const float* __restrict__ tag_score,
    const int* __restrict__ candi_tags, float* __restrict__ out) {
  __shared__ __hip_bfloat16 hl[ROWS][H1n + 8];  // 2.1 KB
  __shared__ float s_part[4][ROWS];
  __shared__ float s_mid[ROWS];

  const int b0 = blockIdx.x * ROWS;
  const int tid = threadIdx.x;
  const int lane = tid & 63;
  const int w = tid >> 6;       // wave 0..3
  const int lr = lane & 15;
  const int lg = lane >> 4;
  const int row4 = lr & 3;      // duplicated batch row index

  // ---- A-fragments: x rows b0+(lr&3), K = 256 (8 k-steps of 32) ----
  short8 a[8];
  {
    const short* xb = reinterpret_cast<const short*>(x_in) +
                      (size_t)(b0 + row4) * (2 * Dn) + 8 * lg;
#pragma unroll
    for (int s = 0; s < 8; ++s) a[s] = *reinterpret_cast<const short8*>(xb + 32 * s);
  }

  // ---- layer 1: wave w covers cols [w*64, w*64+64) ----
#pragma unroll
  for (int t = 0; t < 4; ++t) {
    const int n0 = w * 64 + t * 16;
    f32x4 acc = {0.f, 0.f, 0.f, 0.f};
    const short* wb = reinterpret_cast<const short*>(W1T) +
                      (size_t)(n0 + lr) * (2 * Dn) + 8 * lg;
#pragma unroll
    for (int s = 0; s < 8; ++s) {
      const short8 bfr = *reinterpret_cast<const short8*>(wb + 32 * s);
      acc = __builtin_amdgcn_mfma_f32_16x16x32_bf16(a[s], bfr, acc, 0, 0, 0);
    }
    const int col = n0 + lr;
    const float bias = b1[col];
    if (lg == 0) {  // D rows 0..3 = batch rows 0..3
#pragma unroll
      for (int r = 0; r < 4; ++r) {
        hl[r][col] = __float2bfloat16(fmaxf(acc[r] + bias, 0.f));
      }
    }
  }
  __syncthreads();

  // ---- layer 2: wave w covers cols [w*32, w*32+32) ----
  {
    short8 ah[8];
    const short* hb = reinterpret_cast<const short*>(&hl[0][0]) +
                      row4 * (H1n + 8) + 8 * lg;
#pragma unroll
    for (int s = 0; s < 8; ++s) ah[s] = *reinterpret_cast<const short8*>(hb + 32 * s);

    float pacc[4] = {0.f, 0.f, 0.f, 0.f};
#pragma unroll
    for (int t = 0; t < 2; ++t) {
      const int n0 = w * 32 + t * 16;
      f32x4 acc = {0.f, 0.f, 0.f, 0.f};
      const short* wb = reinterpret_cast<const short*>(W2T) +
                        (size_t)(n0 + lr) * H1n + 8 * lg;
#pragma unroll
      for (int s = 0; s < 8; ++s) {
        const short8 bfr = *reinterpret_cast<const short8*>(wb + 32 * s);
        acc = __builtin_amdgcn_mfma_f32_16x16x32_bf16(ah[s], bfr, acc, 0, 0, 0);
      }
      const int col = n0 + lr;
      const float bias = b2[col];
      const float wr = Wr[col];
#pragma unroll
      for (int r = 0; r < 4; ++r) {
        // D row lg*4+r <-> batch row ((lg*4+r)&3) = r, identical across lg
        pacc[r] += fmaxf(acc[r] + bias, 0.f) * wr;
      }
    }
    // reduce over the 16 lr lanes (masks 1,2,4,8 stay within the lr field)
#pragma unroll
    for (int m = 1; m <= 8; m <<= 1) {
#pragma unroll
      for (int r = 0; r < 4; ++r) pacc[r] += __shfl_xor(pacc[r], m, 64);
    }
    if (lane == 0) {  // lg==0 copy, lr==0 holds the sum
#pragma unroll
      for (int r = 0; r < 4; ++r) s_part[w][r] = pacc[r];
    }
  }
  __syncthreads();

  if (tid < ROWS) {
    s_mid[tid] = s_part[0][tid] + s_part[1][tid] + s_part[2][tid] +
                 s_part[3][tid] + br[0];
  }
  __syncthreads();

  // ---- candidate scores: 400 outputs ----
  for (int i = tid; i < ROWS * Cn; i += 256) {
    const int r = i / Cn;
    const int tg = candi_tags[(size_t)b0 * Cn + i];
    const float v = s_mid[r] + tag_score[tg];
    out[(size_t)b0 * Cn + i] = 1.f / (1.f + __expf(-v));
  }
}

extern "C" void kernel_launch(void* const* d_in, const int* in_sizes, int n_in,
                              void* d_out, int out_size, void* d_ws, size_t ws_size,
                              hipStream_t stream) {
  const int* user_tags  = (const int*)d_in[0];
  const int* user_len   = (const int*)d_in[1];
  const int* item_tags  = (const int*)d_in[2];
  const int* item_len   = (const int*)d_in[3];
  const int* candi_tags = (const int*)d_in[4];
  const float* table    = (const float*)d_in[5];
  const float* W1       = (const float*)d_in[6];
  const float* b1       = (const float*)d_in[7];
  const float* W2       = (const float*)d_in[8];
  const float* b2       = (const float*)d_in[9];
  const float* Wr       = (const float*)d_in[10];
  const float* br       = (const float*)d_in[11];
  float* out = (float*)d_out;

  char* ws = (char*)d_ws;
  float* tag_score       = (float*)(ws);                        // 200000 B
  __hip_bfloat16* tableB = (__hip_bfloat16*)(ws + 204800);      // 12.8 MB
  __hip_bfloat16* x_buf  = (__hip_bfloat16*)(ws + 13004800);    // 2 MB
  __hip_bfloat16* W1T    = (__hip_bfloat16*)(ws + 15101952);    // 128 KB
  __hip_bfloat16* W2T    = (__hip_bfloat16*)(ws + 15233024);    // 64 KB

  // K1: table bf16 cast + tag_score (one streaming pass) + weight prep
  prep_kernel<<<NTBLK + NWPREP, 256, 0, stream>>>(
      table, Wr, W1, W2, tag_score, tableB, W1T, W2T);

  // K2: pooling, one block per batch row, 2 waves per list
  pool_kernel<<<Bn, 256, 0, stream>>>(
      user_tags, user_len, item_tags, item_len, tableB, x_buf);

  // K3: MFMA MLP + scoring, 4 rows per block, 1024 blocks (4/CU)
  mlp_mfma_kernel<<<Bn / ROWS, 256, 0, stream>>>(
      x_buf, W1T, b1, W2T, b2, Wr, br, tag_score, candi_tags, out);
}

// Round 8
// 37.122 us; speedup vs baseline: 1.4538x; 1.4538x over previous
//
#include <hip/hip_runtime.h>
#include <hip/hip_bf16.h>
#include <math.h>

#define Bn 4096
#define Ln 50
#define Cn 100
#define Tn 50000
#define Dn 128
#define H1n 256
#define H2n 128
#define ROWS 16                   // batch rows per mlp block

#define NTBLK (Tn / 4)            // table-prep blocks (4 waves, 1 row each)
#define NWPREP 384                // (256*256 + 128*256) / 256 weight-prep blocks

typedef __attribute__((ext_vector_type(8))) short short8;
typedef __attribute__((ext_vector_type(4))) float f32x4;

// 512-B-row swizzle: byte ^= ((row&7)<<4)  <=>  elem(2B) ^= ((row&7)<<3)
__device__ __forceinline__ int swz(int row, int e) { return e ^ ((row & 7) << 3); }

__device__ __forceinline__ short bf16bits(float f) {
  __hip_bfloat16 h = __float2bfloat16(f);
  return *reinterpret_cast<short*>(&h);
}

// ---------------------------------------------------------------------------
// Kernel 1: table bf16 cast + tag_score + weight prep (weights PRE-SWIZZLED)
// ---------------------------------------------------------------------------
__global__ __launch_bounds__(256) void prep_kernel(
    const float* __restrict__ table, const float* __restrict__ Wr,
    const float* __restrict__ W1, const float* __restrict__ W2,
    float* __restrict__ tag_score, __hip_bfloat16* __restrict__ tableB,
    __hip_bfloat16* __restrict__ W1T, __hip_bfloat16* __restrict__ W2T) {
  const int blk = blockIdx.x;
  const int tid = threadIdx.x;

  if (blk < NTBLK) {
    const int t = blk * 4 + (tid >> 6);   // one wave per table row
    const int lane = tid & 63;
    const float2 v = *reinterpret_cast<const float2*>(table + (size_t)t * Dn + lane * 2);
    const float2 w = *reinterpret_cast<const float2*>(Wr + H2n + lane * 2);
    __hip_bfloat162 o;
    o.x = __float2bfloat16(v.x);
    o.y = __float2bfloat16(v.y);
    *reinterpret_cast<__hip_bfloat162*>(tableB + (size_t)t * Dn + lane * 2) = o;
    float acc = v.x * w.x + v.y * w.y;
#pragma unroll
    for (int m = 32; m >= 1; m >>= 1) acc += __shfl_xor(acc, m, 64);
    if (lane == 0) tag_score[t] = acc;
  } else {
    int id = (blk - NTBLK) * 256 + tid;
    if (id < H1n * H1n) {
      const int j = id >> 8, k = id & 255;       // j = out col, k = K index
      W1T[j * 256 + swz(j, k)] = __float2bfloat16(W1[(size_t)k * H1n + j]);
    } else {
      id -= H1n * H1n;
      const int j = id >> 8, k = id & 255;       // j < 128, k < 256
      W2T[j * 256 + swz(j, k)] = __float2bfloat16(W2[(size_t)k * H2n + j]);
    }
  }
}

// ---------------------------------------------------------------------------
// Kernel 2: masked-mean pooling (unchanged structure; x written PRE-SWIZZLED)
// ---------------------------------------------------------------------------
__global__ __launch_bounds__(256) void pool_kernel(
    const int* __restrict__ user_tags, const int* __restrict__ user_len,
    const int* __restrict__ item_tags, const int* __restrict__ item_len,
    const __hip_bfloat16* __restrict__ tableB, __hip_bfloat16* __restrict__ x_out) {
  __shared__ int s_tags[2][Ln];
  __shared__ float2 s_acc[2][64];
  const int b = blockIdx.x;
  const int tid = threadIdx.x;

  if (tid < Ln) s_tags[0][tid] = user_tags[b * Ln + tid];
  else if (tid >= 128 && tid < 128 + Ln) s_tags[1][tid - 128] = item_tags[b * Ln + (tid - 128)];
  __syncthreads();

  const int w = tid >> 6;         // wave 0..3
  const int half = w >> 1;        // 0 = user, 1 = item
  const int par = w & 1;          // position parity handled by this wave
  const int lane = tid & 63;
  const int len = half ? item_len[b] : user_len[b];
  const int* tags = s_tags[half];

  const __hip_bfloat162* base =
      reinterpret_cast<const __hip_bfloat162*>(tableB) + lane;  // + t*64

  float a0 = 0.f, a1 = 0.f;
  int l = par;
  for (; l + 14 < len; l += 16) {
    __hip_bfloat162 v[8];
#pragma unroll
    for (int q = 0; q < 8; ++q) v[q] = base[(size_t)tags[l + 2 * q] * 64];
#pragma unroll
    for (int q = 0; q < 8; ++q) {
      a0 += __bfloat162float(v[q].x);
      a1 += __bfloat162float(v[q].y);
    }
  }
  for (; l + 6 < len; l += 8) {
    __hip_bfloat162 v[4];
#pragma unroll
    for (int q = 0; q < 4; ++q) v[q] = base[(size_t)tags[l + 2 * q] * 64];
#pragma unroll
    for (int q = 0; q < 4; ++q) {
      a0 += __bfloat162float(v[q].x);
      a1 += __bfloat162float(v[q].y);
    }
  }
  for (; l < len; l += 2) {
    const __hip_bfloat162 v = base[(size_t)tags[l] * 64];
    a0 += __bfloat162float(v.x);
    a1 += __bfloat162float(v.y);
  }

  if (par == 1) s_acc[half][lane] = make_float2(a0, a1);
  __syncthreads();
  if (par == 0) {
    a0 += s_acc[half][lane].x;
    a1 += s_acc[half][lane].y;
    const float inv = 1.f / (float)(len > 0 ? len : 1);
    __hip_bfloat162 o;
    o.x = __float2bfloat16(a0 * inv);
    o.y = __float2bfloat16(a1 * inv);
    const int d0 = half * Dn + 2 * lane;
    // pre-swizzled write (b&7 == local-row&7 since tiles are 16-aligned)
    *reinterpret_cast<__hip_bfloat162*>(
        x_out + (size_t)b * (2 * Dn) + swz(b, d0)) = o;
  }
}

// ---------------------------------------------------------------------------
// Kernel 3: LDS-staged MFMA MLP + scoring. 256 threads (4 waves), 16 rows.
// Canonical structure: global_load_lds (coalesced, linear) -> swizzled
// ds_read_b128 fragments -> MFMA. Weight chunks double-buffered.
// ---------------------------------------------------------------------------
__global__ __launch_bounds__(256) void mlp_mfma_kernel(
    const __hip_bfloat16* __restrict__ x_in, const __hip_bfloat16* __restrict__ W1T,
    const float* __restrict__ b1, const __hip_bfloat16* __restrict__ W2T,
    const float* __restrict__ b2, const float* __restrict__ Wr,
    const float* __restrict__ br, const float* __restrict__ tag_score,
    const int* __restrict__ candi_tags, float* __restrict__ out) {
  __shared__ __align__(16) short xh[ROWS * 256];       // 8 KB: x-tile, then h-tile
  __shared__ __align__(16) short wbuf[2][64 * 256];    // 2 x 32 KB weight chunks
  __shared__ float s_part[4][ROWS];
  __shared__ float s_mid[ROWS];

  const int b0 = blockIdx.x * ROWS;
  const int tid = threadIdx.x;
  const int lane = tid & 63;
  const int w = tid >> 6;       // wave 0..3
  const int lr = lane & 15;
  const int lg = lane >> 4;

  // coalesced staging: 1-KB slices (64 lanes x 16 B), wave-strided
  auto stage = [&](short* ldsbase, const short* gsrc, int nbytes) {
    const int nslice = nbytes >> 10;
    for (int r = w; r < nslice; r += 4) {
      __builtin_amdgcn_global_load_lds(
          (const __attribute__((address_space(1))) void*)((const char*)gsrc + r * 1024 + lane * 16),
          (__attribute__((address_space(3))) void*)((char*)ldsbase + r * 1024),
          16, 0, 0);
    }
  };

  stage(xh, (const short*)x_in + (size_t)b0 * 256, 8192);
  stage(wbuf[0], (const short*)W1T, 32768);            // W1 cols [0,64)
  __syncthreads();                                      // drains vmcnt

  // ---- A-fragments from x-tile (row lr, 8 k-steps) ----
  short8 a[8];
#pragma unroll
  for (int s = 0; s < 8; ++s)
    a[s] = *reinterpret_cast<const short8*>(&xh[lr * 256 + swz(lr, 8 * lg + 32 * s)]);
  __syncthreads();  // all x reads done before h overwrites xh

  // ---- layer 1: 4 chunks of 64 cols; wave w -> tile cols [c*64+w*16, +16) ----
#pragma unroll
  for (int c = 0; c < 4; ++c) {
    if (c < 3) stage(wbuf[(c + 1) & 1], (const short*)W1T + (c + 1) * 64 * 256, 32768);
    else       stage(wbuf[0],           (const short*)W2T,                      32768);

    const int cc = w * 16 + lr;       // col within chunk
    f32x4 acc = {0.f, 0.f, 0.f, 0.f};
#pragma unroll
    for (int s = 0; s < 8; ++s) {
      const short8 bfr = *reinterpret_cast<const short8*>(
          &wbuf[c & 1][cc * 256 + swz(cc, 8 * lg + 32 * s)]);
      acc = __builtin_amdgcn_mfma_f32_16x16x32_bf16(a[s], bfr, acc, 0, 0, 0);
    }
    const int col = c * 64 + cc;
    const float bias = b1[col];
#pragma unroll
    for (int r = 0; r < 4; ++r) {
      const int row = lg * 4 + r;
      xh[row * 256 + swz(row, col)] = bf16bits(fmaxf(acc[r] + bias, 0.f));
    }
    __syncthreads();  // drains next-chunk vmcnt; h-writes visible
  }

  // ---- layer 2: A2 = h-tile; W2 chunks 0 (staged) and 1 ----
  short8 a2[8];
#pragma unroll
  for (int s = 0; s < 8; ++s)
    a2[s] = *reinterpret_cast<const short8*>(&xh[lr * 256 + swz(lr, 8 * lg + 32 * s)]);

  float pacc[4] = {0.f, 0.f, 0.f, 0.f};
#pragma unroll
  for (int c2 = 0; c2 < 2; ++c2) {
    if (c2 == 0) stage(wbuf[1], (const short*)W2T + 64 * 256, 32768);
    const int cc = w * 16 + lr;
    f32x4 acc = {0.f, 0.f, 0.f, 0.f};
#pragma unroll
    for (int s = 0; s < 8; ++s) {
      const short8 bfr = *reinterpret_cast<const short8*>(
          &wbuf[c2][cc * 256 + swz(cc, 8 * lg + 32 * s)]);
      acc = __builtin_amdgcn_mfma_f32_16x16x32_bf16(a2[s], bfr, acc, 0, 0, 0);
    }
    const int col = c2 * 64 + cc;
    const float bias = b2[col];
    const float wr = Wr[col];
#pragma unroll
    for (int r = 0; r < 4; ++r) pacc[r] += fmaxf(acc[r] + bias, 0.f) * wr;
    if (c2 == 0) __syncthreads();
  }

  // reduce over the 16 lr-lanes (masks stay within the lr field)
#pragma unroll
  for (int m = 1; m <= 8; m <<= 1) {
#pragma unroll
    for (int r = 0; r < 4; ++r) pacc[r] += __shfl_xor(pacc[r], m, 64);
  }
  if (lr == 0) {
#pragma unroll
    for (int r = 0; r < 4; ++r) s_part[w][lg * 4 + r] = pacc[r];
  }
  __syncthreads();

  if (tid < ROWS) {
    s_mid[tid] = s_part[0][tid] + s_part[1][tid] + s_part[2][tid] +
                 s_part[3][tid] + br[0];
  }
  __syncthreads();

  // ---- candidate scores: 1600 outputs ----
  for (int i = tid; i < ROWS * Cn; i += 256) {
    const int r = i / Cn;
    const int tg = candi_tags[(size_t)b0 * Cn + i];
    const float v = s_mid[r] + tag_score[tg];
    out[(size_t)b0 * Cn + i] = 1.f / (1.f + __expf(-v));
  }
}

extern "C" void kernel_launch(void* const* d_in, const int* in_sizes, int n_in,
                              void* d_out, int out_size, void* d_ws, size_t ws_size,
                              hipStream_t stream) {
  const int* user_tags  = (const int*)d_in[0];
  const int* user_len   = (const int*)d_in[1];
  const int* item_tags  = (const int*)d_in[2];
  const int* item_len   = (const int*)d_in[3];
  const int* candi_tags = (const int*)d_in[4];
  const float* table    = (const float*)d_in[5];
  const float* W1       = (const float*)d_in[6];
  const float* b1       = (const float*)d_in[7];
  const float* W2       = (const float*)d_in[8];
  const float* b2       = (const float*)d_in[9];
  const float* Wr       = (const float*)d_in[10];
  const float* br       = (const float*)d_in[11];
  float* out = (float*)d_out;

  char* ws = (char*)d_ws;
  float* tag_score       = (float*)(ws);                        // 200000 B
  __hip_bfloat16* tableB = (__hip_bfloat16*)(ws + 204800);      // 12.8 MB
  __hip_bfloat16* x_buf  = (__hip_bfloat16*)(ws + 13004800);    // 2 MB
  __hip_bfloat16* W1T    = (__hip_bfloat16*)(ws + 15101952);    // 128 KB
  __hip_bfloat16* W2T    = (__hip_bfloat16*)(ws + 15233024);    // 64 KB

  // K1: table bf16 cast + tag_score + weight prep (pre-swizzled)
  prep_kernel<<<NTBLK + NWPREP, 256, 0, stream>>>(
      table, Wr, W1, W2, tag_score, tableB, W1T, W2T);

  // K2: pooling, one block per batch row (x pre-swizzled)
  pool_kernel<<<Bn, 256, 0, stream>>>(
      user_tags, user_len, item_tags, item_len, tableB, x_buf);

  // K3: LDS-staged MFMA MLP + scoring, 16 rows per block
  mlp_mfma_kernel<<<Bn / ROWS, 256, 0, stream>>>(
      x_buf, W1T, b1, W2T, b2, Wr, br, tag_score, candi_tags, out);
}